// Round 8
// baseline (271.947 us; speedup 1.0000x reference)
//
#include <hip/hip_runtime.h>
#include <hip/hip_bf16.h>

typedef __bf16 bf16x8 __attribute__((ext_vector_type(8)));
typedef float  f32x4  __attribute__((ext_vector_type(4)));

#define NHEAD 5

// ---------------- kernel 0: x fp32 [b][c][d][hw] -> xbf bf16 [ls][p][c] ----------------
__global__ __launch_bounds__(256) void k0_xpose(const float* __restrict__ x,
                                                __bf16* __restrict__ xbf,
                                                int slice_base) {
  int blk = blockIdx.x;
  int ls = blk >> 4;           // local slice in chunk
  int pt = blk & 15;           // 256-position tile
  int g  = slice_base + ls;
  int b = g >> 3, d = g & 7;
  __shared__ __attribute__((aligned(16))) float xs[64][257];
  const int t = threadIdx.x;
  const int wv = t >> 6, l = t & 63;
  const float* xbase = x + (((size_t)b * 64) * 8 + d) * 4096 + pt * 256;
  for (int i = 0; i < 16; ++i) {
    int row = i * 4 + wv;
    int col = l * 4;
    float4 v = *(const float4*)(xbase + (size_t)row * 32768 + col);
    xs[row][col + 0] = v.x; xs[row][col + 1] = v.y;
    xs[row][col + 2] = v.z; xs[row][col + 3] = v.w;
  }
  __syncthreads();
  for (int i = 0; i < 8; ++i) {
    int chunk = i * 256 + t;
    int p = chunk >> 3, cb = chunk & 7;
    bf16x8 o;
    for (int j = 0; j < 8; ++j) o[j] = (__bf16)xs[cb * 8 + j][p];
    *(bf16x8*)(xbf + ((size_t)ls * 4096 + pt * 256 + p) * 64 + cb * 8) = o;
  }
}

// ---------------- kernel 1: qkv[ls][o][hw] = W[o][c] * x[c][hw] + bias[o] ----------------
__global__ __launch_bounds__(256) void k1_qkv(const __bf16* __restrict__ xbf,
                                              const float* __restrict__ W,
                                              const float* __restrict__ bias,
                                              __bf16* __restrict__ qkv,
                                              int slice_base) {
  int blk = blockIdx.x;
  int ls = blk / 240;
  int r  = blk % 240;
  int ot = r >> 4;             // 15 o-tiles of 64 channels
  int pt = r & 15;             // 16 p-tiles of 256 positions
  int o0 = ot * 64;
  __shared__ __attribute__((aligned(16))) __bf16 wlds[64 * 72];
  __shared__ float blds[64];
  __shared__ __attribute__((aligned(16))) __bf16 xt[256 * 72];   // reused as repack buf
  const int t = threadIdx.x;
  for (int i = 0; i < 4; ++i) {
    int e = i * 1024 + t * 4;
    int row = e >> 6, col = e & 63;
    float4 v = *(const float4*)(W + (size_t)o0 * 64 + e);
    __bf16* dst = wlds + row * 72 + col;
    dst[0] = (__bf16)v.x; dst[1] = (__bf16)v.y; dst[2] = (__bf16)v.z; dst[3] = (__bf16)v.w;
  }
  if (t < 64) blds[t] = bias[o0 + t];
  const __bf16* xsrc = xbf + (size_t)ls * 262144 + (size_t)pt * 16384;
  for (int i = 0; i < 8; ++i) {
    int e = (i * 256 + t) * 8;
    int p = e >> 6, c0 = e & 63;
    *(bf16x8*)(xt + p * 72 + c0) = *(const bf16x8*)(xsrc + e);
  }
  __syncthreads();
  const int wv = t >> 6, l = t & 63;
  const int lr = l & 15, g4 = l >> 4;
  const f32x4 zero4 = {0.f, 0.f, 0.f, 0.f};
  bf16x8 a0 = *(const bf16x8*)(wlds + (16 * wv + lr) * 72 + g4 * 8);
  bf16x8 a1 = *(const bf16x8*)(wlds + (16 * wv + lr) * 72 + 32 + g4 * 8);
  f32x4 acc[16];
  for (int i = 0; i < 16; ++i) acc[i] = zero4;
  for (int p2 = 0; p2 < 16; ++p2) {
    const __bf16* xrow = xt + (p2 * 16 + lr) * 72 + g4 * 8;
    bf16x8 b0 = *(const bf16x8*)(xrow);
    bf16x8 b1 = *(const bf16x8*)(xrow + 32);
    acc[p2] = __builtin_amdgcn_mfma_f32_16x16x32_bf16(a0, b0, acc[p2], 0, 0, 0);
    acc[p2] = __builtin_amdgcn_mfma_f32_16x16x32_bf16(a1, b1, acc[p2], 0, 0, 0);
  }
  float bv[4];
  for (int rr = 0; rr < 4; ++rr) bv[rr] = blds[16 * wv + 4 * g4 + rr];
  __syncthreads();
  __bf16* rp = xt;                       // repack as [64 o][264 p]
  for (int p2 = 0; p2 < 16; ++p2)
    for (int rr = 0; rr < 4; ++rr) {
      int o_l = 16 * wv + 4 * g4 + rr;
      rp[o_l * 264 + p2 * 16 + lr] = (__bf16)(acc[p2][rr] + bv[rr]);
    }
  __syncthreads();
  for (int i = 0; i < 8; ++i) {
    int chunk = i * 256 + t;
    int row = chunk >> 5, cb = chunk & 31;
    bf16x8 v = *(const bf16x8*)(rp + row * 264 + cb * 8);
    *(bf16x8*)(qkv + ((size_t)ls * 960 + o0 + row) * 4096 + (size_t)pt * 256 + cb * 8) = v;
  }
}

// ---------------- kernel 2: one attention per block, 24 KB LDS, 6 blocks/CU ----------------
// buf slots: 0=Q (-> fp32 bounce lo), 1=K -> P (-> bounce hi), 2=Vt. All XOR-swizzled.
__global__ __launch_bounds__(256, 6) void k2_attn(const __bf16* __restrict__ qkv,
                                                  const float* __restrict__ x,
                                                  const float* __restrict__ gamma,
                                                  float* __restrict__ out,
                                                  int slice_base) {
  __shared__ __attribute__((aligned(16))) __bf16 buf[3][4096];
  int nb = blockIdx.x;
  int ls = nb / 320;
  int r  = nb % 320;
  int n  = r >> 6;               // head
  int c  = r & 63;               // channel
  int g = slice_base + ls;
  int b = g >> 3, d = g & 7;

  const int t = threadIdx.x;
  const int wv = t >> 6, l = t & 63, lr = l & 15, g4 = l >> 4;
  const int i0 = wv * 16;
  const int srow = t >> 2;           // staging row 0..63
  const int scol = (t & 3) * 16;     // staging col base
  const f32x4 zero4 = {0.f, 0.f, 0.f, 0.f};

  const __bf16* qp = qkv + (size_t)(ls * 960 + n * 192 + c) * 4096;
  const __bf16* kp = qp + (size_t)64 * 4096;
  const __bf16* vp = qp + (size_t)128 * 4096;

  // ---- stage Q, K (row-major) and V (transposed), all XOR-swizzled ----
  {
    bf16x8 rq0 = *(const bf16x8*)(qp + srow * 64 + scol);
    bf16x8 rq1 = *(const bf16x8*)(qp + srow * 64 + scol + 8);
    bf16x8 rk0 = *(const bf16x8*)(kp + srow * 64 + scol);
    bf16x8 rk1 = *(const bf16x8*)(kp + srow * 64 + scol + 8);
    bf16x8 rv0 = *(const bf16x8*)(vp + srow * 64 + scol);
    bf16x8 rv1 = *(const bf16x8*)(vp + srow * 64 + scol + 8);
    int a0 = (srow * 64 + scol) ^ ((srow & 7) << 3);
    int a1 = (srow * 64 + scol + 8) ^ ((srow & 7) << 3);
    *(bf16x8*)(&buf[0][a0]) = rq0;
    *(bf16x8*)(&buf[0][a1]) = rq1;
    *(bf16x8*)(&buf[1][a0]) = rk0;
    *(bf16x8*)(&buf[1][a1]) = rk1;
#pragma unroll
    for (int kk = 0; kk < 8; ++kk) {
      int w0 = scol + kk, w1 = scol + 8 + kk;
      buf[2][(w0 * 64 + srow) ^ ((w0 & 7) << 3)] = rv0[kk];
      buf[2][(w1 * 64 + srow) ^ ((w1 & 7) << 3)] = rv1[kk];
    }
  }

  // ---- prefetch x residual (used only in the epilogue, ~whole kernel of cover) ----
  f32x4 xpre[4];
  int o2 = c * NHEAD + n;
  int np = o2 >> 6, fp = o2 & 63;
  {
    const float* xp = x + (((size_t)b * 64 + fp) * 8 + d) * 4096 + t * 16;
    xpre[0] = *(const f32x4*)(xp);
    xpre[1] = *(const f32x4*)(xp + 4);
    xpre[2] = *(const f32x4*)(xp + 8);
    xpre[3] = *(const f32x4*)(xp + 12);
  }
  __syncthreads();

  // ---- QK^T: sim[i][j] = sum_w K[i][w] Q[j][w] ----
  f32x4 sacc[4];
#pragma unroll
  for (int jt = 0; jt < 4; ++jt) sacc[jt] = zero4;
  bf16x8 ka0, ka1;
  {
    int ia = i0 + lr;
    ka0 = *(const bf16x8*)(&buf[1][(ia * 64 + g4 * 8) ^ ((ia & 7) << 3)]);
    ka1 = *(const bf16x8*)(&buf[1][(ia * 64 + 32 + g4 * 8) ^ ((ia & 7) << 3)]);
  }
#pragma unroll
  for (int jt = 0; jt < 4; ++jt) {
    int ja = jt * 16 + lr;
    bf16x8 qb0 = *(const bf16x8*)(&buf[0][(ja * 64 + g4 * 8) ^ ((ja & 7) << 3)]);
    bf16x8 qb1 = *(const bf16x8*)(&buf[0][(ja * 64 + 32 + g4 * 8) ^ ((ja & 7) << 3)]);
    sacc[jt] = __builtin_amdgcn_mfma_f32_16x16x32_bf16(ka0, qb0, sacc[jt], 0, 0, 0);
    sacc[jt] = __builtin_amdgcn_mfma_f32_16x16x32_bf16(ka1, qb1, sacc[jt], 0, 0, 0);
  }

  // ---- softmax over j ----
  float pr[4][4];
#pragma unroll
  for (int rr = 0; rr < 4; ++rr) {
    float m = fmaxf(fmaxf(sacc[0][rr], sacc[1][rr]), fmaxf(sacc[2][rr], sacc[3][rr]));
#pragma unroll
    for (int dd = 1; dd < 16; dd <<= 1) m = fmaxf(m, __shfl_xor(m, dd));
    float s = 0.f;
#pragma unroll
    for (int jt = 0; jt < 4; ++jt) {
      pr[jt][rr] = __expf(sacc[jt][rr] - m);
      s += pr[jt][rr];
    }
#pragma unroll
    for (int dd = 1; dd < 16; dd <<= 1) s += __shfl_xor(s, dd);
    float inv = 1.0f / s;
#pragma unroll
    for (int jt = 0; jt < 4; ++jt) pr[jt][rr] *= inv;
  }
  __syncthreads();                   // Q,K reads done

  // ---- write P into dead K slot ----
#pragma unroll
  for (int jt = 0; jt < 4; ++jt)
#pragma unroll
    for (int rr = 0; rr < 4; ++rr) {
      int i = i0 + 4 * g4 + rr;
      int j = jt * 16 + lr;
      buf[1][(i * 64 + j) ^ ((i & 7) << 3)] = (__bf16)pr[jt][rr];
    }
  __syncthreads();                   // P visible

  // ---- PV: pv[i][w] = sum_j P[i][j] V[j][w] ----
  f32x4 pacc[4];
#pragma unroll
  for (int wt = 0; wt < 4; ++wt) pacc[wt] = zero4;
  bf16x8 aa0, aa1;
  {
    int ia = i0 + lr;
    aa0 = *(const bf16x8*)(&buf[1][(ia * 64 + g4 * 8) ^ ((ia & 7) << 3)]);
    aa1 = *(const bf16x8*)(&buf[1][(ia * 64 + 32 + g4 * 8) ^ ((ia & 7) << 3)]);
  }
#pragma unroll
  for (int wt = 0; wt < 4; ++wt) {
    int wrow = wt * 16 + lr;
    bf16x8 vb0 = *(const bf16x8*)(&buf[2][(wrow * 64 + g4 * 8) ^ ((wrow & 7) << 3)]);
    bf16x8 vb1 = *(const bf16x8*)(&buf[2][(wrow * 64 + 32 + g4 * 8) ^ ((wrow & 7) << 3)]);
    pacc[wt] = __builtin_amdgcn_mfma_f32_16x16x32_bf16(aa0, vb0, pacc[wt], 0, 0, 0);
    pacc[wt] = __builtin_amdgcn_mfma_f32_16x16x32_bf16(aa1, vb1, pacc[wt], 0, 0, 0);
  }
  __syncthreads();                   // P,Vt reads done

  // ---- bounce PV fp32 through dead Q+K slots ----
  float* fb = (float*)&buf[0][0];    // 8192 bf16 = 4096 floats
#pragma unroll
  for (int wt = 0; wt < 4; ++wt)
#pragma unroll
    for (int rr = 0; rr < 4; ++rr) {
      int i = i0 + 4 * g4 + rr;
      int w = wt * 16 + lr;
      fb[(i * 64 + w) ^ ((i & 7) << 2)] = pacc[wt][rr];
    }
  __syncthreads();                   // bounce visible

  // ---- vectorized epilogue: out = gamma*pv + x (nontemporal: don't evict qkv from L3) ----
  {
    int oc = fp * NHEAD + np;
    float gm = gamma[np];
    int ib = t >> 2;                 // row index of this thread's 16 floats
    int xs_ = ((ib & 7) << 2);
    f32x4 p0 = *(const f32x4*)(fb + ((t * 16 + 0) ^ xs_));
    f32x4 p1 = *(const f32x4*)(fb + ((t * 16 + 4) ^ xs_));
    f32x4 p2 = *(const f32x4*)(fb + ((t * 16 + 8) ^ xs_));
    f32x4 p3 = *(const f32x4*)(fb + ((t * 16 + 12) ^ xs_));
    f32x4 o0, o1, o2v, o3;
#pragma unroll
    for (int j = 0; j < 4; ++j) {
      o0[j]  = gm * p0[j] + xpre[0][j];
      o1[j]  = gm * p1[j] + xpre[1][j];
      o2v[j] = gm * p2[j] + xpre[2][j];
      o3[j]  = gm * p3[j] + xpre[3][j];
    }
    float* op = out + (((size_t)b * 320 + oc) * 8 + d) * 4096 + t * 16;
    __builtin_nontemporal_store(o0,  (f32x4*)(op + 0));
    __builtin_nontemporal_store(o1,  (f32x4*)(op + 4));
    __builtin_nontemporal_store(o2v, (f32x4*)(op + 8));
    __builtin_nontemporal_store(o3,  (f32x4*)(op + 12));
  }
}

extern "C" void kernel_launch(void* const* d_in, const int* in_sizes, int n_in,
                              void* d_out, int out_size, void* d_ws, size_t ws_size,
                              hipStream_t stream) {
  const float* x     = (const float*)d_in[0];
  const float* W     = (const float*)d_in[1];
  const float* bias  = (const float*)d_in[2];
  const float* gamma = (const float*)d_in[3];
  float* out = (float*)d_out;

  // per (b,d) slice: xbf = 524288 B ; qkv = 7864320 B
  const size_t per_slice = 524288 + 7864320;   // 8 MB
  int S = (int)(ws_size / per_slice);
  if (S > 32) S = 32;
  if (S < 1)  S = 1;
  __bf16* xbf = (__bf16*)d_ws;
  __bf16* qkv = (__bf16*)((char*)d_ws + (size_t)S * 524288);

  for (int sb = 0; sb < 32; sb += S) {
    int sc = 32 - sb; if (sc > S) sc = S;
    k0_xpose<<<16  * sc, 256, 0, stream>>>(x, xbf, sb);
    k1_qkv  <<<240 * sc, 256, 0, stream>>>(xbf, W, bias, qkv, sb);
    k2_attn <<<320 * sc, 256, 0, stream>>>(qkv, x, gamma, out, sb);
  }
}

// Round 9
// 182.419 us; speedup vs baseline: 1.4908x; 1.4908x over previous
//
#include <hip/hip_runtime.h>
#include <hip/hip_bf16.h>

typedef __bf16 bf16x8 __attribute__((ext_vector_type(8)));
typedef float  f32x4  __attribute__((ext_vector_type(4)));

#define NHEAD 5

// ---------------- kernel 0: x fp32 [b][c][d][hw] -> xbf bf16 [ls][p][c] ----------------
__global__ __launch_bounds__(256) void k0_xpose(const float* __restrict__ x,
                                                __bf16* __restrict__ xbf,
                                                int slice_base) {
  int blk = blockIdx.x;
  int ls = blk >> 4;           // local slice in chunk
  int pt = blk & 15;           // 256-position tile
  int g  = slice_base + ls;
  int b = g >> 3, d = g & 7;
  __shared__ __attribute__((aligned(16))) float xs[64][257];
  const int t = threadIdx.x;
  const int wv = t >> 6, l = t & 63;
  const float* xbase = x + (((size_t)b * 64) * 8 + d) * 4096 + pt * 256;
  for (int i = 0; i < 16; ++i) {
    int row = i * 4 + wv;
    int col = l * 4;
    float4 v = *(const float4*)(xbase + (size_t)row * 32768 + col);
    xs[row][col + 0] = v.x; xs[row][col + 1] = v.y;
    xs[row][col + 2] = v.z; xs[row][col + 3] = v.w;
  }
  __syncthreads();
  for (int i = 0; i < 8; ++i) {
    int chunk = i * 256 + t;
    int p = chunk >> 3, cb = chunk & 7;
    bf16x8 o;
    for (int j = 0; j < 8; ++j) o[j] = (__bf16)xs[cb * 8 + j][p];
    *(bf16x8*)(xbf + ((size_t)ls * 4096 + pt * 256 + p) * 64 + cb * 8) = o;
  }
}

// ---------------- kernel 1: qkv[ls][o][hw] = W[o][c] * x[c][hw] + bias[o] ----------------
__global__ __launch_bounds__(256) void k1_qkv(const __bf16* __restrict__ xbf,
                                              const float* __restrict__ W,
                                              const float* __restrict__ bias,
                                              __bf16* __restrict__ qkv,
                                              int slice_base) {
  int blk = blockIdx.x;
  int ls = blk / 240;
  int r  = blk % 240;
  int ot = r >> 4;             // 15 o-tiles of 64 channels
  int pt = r & 15;             // 16 p-tiles of 256 positions
  int o0 = ot * 64;
  __shared__ __attribute__((aligned(16))) __bf16 wlds[64 * 72];
  __shared__ float blds[64];
  __shared__ __attribute__((aligned(16))) __bf16 xt[256 * 72];   // reused as repack buf
  const int t = threadIdx.x;
  for (int i = 0; i < 4; ++i) {
    int e = i * 1024 + t * 4;
    int row = e >> 6, col = e & 63;
    float4 v = *(const float4*)(W + (size_t)o0 * 64 + e);
    __bf16* dst = wlds + row * 72 + col;
    dst[0] = (__bf16)v.x; dst[1] = (__bf16)v.y; dst[2] = (__bf16)v.z; dst[3] = (__bf16)v.w;
  }
  if (t < 64) blds[t] = bias[o0 + t];
  const __bf16* xsrc = xbf + (size_t)ls * 262144 + (size_t)pt * 16384;
  for (int i = 0; i < 8; ++i) {
    int e = (i * 256 + t) * 8;
    int p = e >> 6, c0 = e & 63;
    *(bf16x8*)(xt + p * 72 + c0) = *(const bf16x8*)(xsrc + e);
  }
  __syncthreads();
  const int wv = t >> 6, l = t & 63;
  const int lr = l & 15, g4 = l >> 4;
  const f32x4 zero4 = {0.f, 0.f, 0.f, 0.f};
  bf16x8 a0 = *(const bf16x8*)(wlds + (16 * wv + lr) * 72 + g4 * 8);
  bf16x8 a1 = *(const bf16x8*)(wlds + (16 * wv + lr) * 72 + 32 + g4 * 8);
  f32x4 acc[16];
  for (int i = 0; i < 16; ++i) acc[i] = zero4;
  for (int p2 = 0; p2 < 16; ++p2) {
    const __bf16* xrow = xt + (p2 * 16 + lr) * 72 + g4 * 8;
    bf16x8 b0 = *(const bf16x8*)(xrow);
    bf16x8 b1 = *(const bf16x8*)(xrow + 32);
    acc[p2] = __builtin_amdgcn_mfma_f32_16x16x32_bf16(a0, b0, acc[p2], 0, 0, 0);
    acc[p2] = __builtin_amdgcn_mfma_f32_16x16x32_bf16(a1, b1, acc[p2], 0, 0, 0);
  }
  float bv[4];
  for (int rr = 0; rr < 4; ++rr) bv[rr] = blds[16 * wv + 4 * g4 + rr];
  __syncthreads();
  __bf16* rp = xt;                       // repack as [64 o][264 p]
  for (int p2 = 0; p2 < 16; ++p2)
    for (int rr = 0; rr < 4; ++rr) {
      int o_l = 16 * wv + 4 * g4 + rr;
      rp[o_l * 264 + p2 * 16 + lr] = (__bf16)(acc[p2][rr] + bv[rr]);
    }
  __syncthreads();
  for (int i = 0; i < 8; ++i) {
    int chunk = i * 256 + t;
    int row = chunk >> 5, cb = chunk & 31;
    bf16x8 v = *(const bf16x8*)(rp + row * 264 + cb * 8);
    *(bf16x8*)(qkv + ((size_t)ls * 960 + o0 + row) * 4096 + (size_t)pt * 256 + cb * 8) = v;
  }
}

// ---------------- kernel 2: one attention per block, 24 KB LDS ----------------
// buf slots: 0=Q (-> fp32 bounce lo), 1=K -> P (-> bounce hi), 2=Vt. All XOR-swizzled.
__global__ __launch_bounds__(256, 3) void k2_attn(const __bf16* __restrict__ qkv,
                                                  const float* __restrict__ x,
                                                  const float* __restrict__ gamma,
                                                  float* __restrict__ out,
                                                  int slice_base) {
  __shared__ __attribute__((aligned(16))) __bf16 buf[3][4096];
  int nb = blockIdx.x;
  int ls = nb / 320;
  int r  = nb % 320;
  int n  = r >> 6;               // head
  int c  = r & 63;               // channel
  int g = slice_base + ls;
  int b = g >> 3, d = g & 7;

  const int t = threadIdx.x;
  const int wv = t >> 6, l = t & 63, lr = l & 15, g4 = l >> 4;
  const int i0 = wv * 16;
  const int srow = t >> 2;           // staging row 0..63
  const int scol = (t & 3) * 16;     // staging col base
  const f32x4 zero4 = {0.f, 0.f, 0.f, 0.f};

  const __bf16* qp = qkv + (size_t)(ls * 960 + n * 192 + c) * 4096;
  const __bf16* kp = qp + (size_t)64 * 4096;
  const __bf16* vp = qp + (size_t)128 * 4096;

  // ---- stage Q, K (row-major) and V (transposed), all XOR-swizzled ----
  {
    bf16x8 rq0 = *(const bf16x8*)(qp + srow * 64 + scol);
    bf16x8 rq1 = *(const bf16x8*)(qp + srow * 64 + scol + 8);
    bf16x8 rk0 = *(const bf16x8*)(kp + srow * 64 + scol);
    bf16x8 rk1 = *(const bf16x8*)(kp + srow * 64 + scol + 8);
    bf16x8 rv0 = *(const bf16x8*)(vp + srow * 64 + scol);
    bf16x8 rv1 = *(const bf16x8*)(vp + srow * 64 + scol + 8);
    int a0 = (srow * 64 + scol) ^ ((srow & 7) << 3);
    int a1 = (srow * 64 + scol + 8) ^ ((srow & 7) << 3);
    *(bf16x8*)(&buf[0][a0]) = rq0;
    *(bf16x8*)(&buf[0][a1]) = rq1;
    *(bf16x8*)(&buf[1][a0]) = rk0;
    *(bf16x8*)(&buf[1][a1]) = rk1;
#pragma unroll
    for (int kk = 0; kk < 8; ++kk) {
      int w0 = scol + kk, w1 = scol + 8 + kk;
      buf[2][(w0 * 64 + srow) ^ ((w0 & 7) << 3)] = rv0[kk];
      buf[2][(w1 * 64 + srow) ^ ((w1 & 7) << 3)] = rv1[kk];
    }
  }

  // ---- prefetch x residual (used only in the epilogue) ----
  f32x4 xpre[4];
  int o2 = c * NHEAD + n;
  int np = o2 >> 6, fp = o2 & 63;
  {
    const float* xp = x + (((size_t)b * 64 + fp) * 8 + d) * 4096 + t * 16;
    xpre[0] = *(const f32x4*)(xp);
    xpre[1] = *(const f32x4*)(xp + 4);
    xpre[2] = *(const f32x4*)(xp + 8);
    xpre[3] = *(const f32x4*)(xp + 12);
  }
  __syncthreads();

  // ---- QK^T: sim[i][j] = sum_w K[i][w] Q[j][w] ----
  f32x4 sacc[4];
#pragma unroll
  for (int jt = 0; jt < 4; ++jt) sacc[jt] = zero4;
  bf16x8 ka0, ka1;
  {
    int ia = i0 + lr;
    ka0 = *(const bf16x8*)(&buf[1][(ia * 64 + g4 * 8) ^ ((ia & 7) << 3)]);
    ka1 = *(const bf16x8*)(&buf[1][(ia * 64 + 32 + g4 * 8) ^ ((ia & 7) << 3)]);
  }
#pragma unroll
  for (int jt = 0; jt < 4; ++jt) {
    int ja = jt * 16 + lr;
    bf16x8 qb0 = *(const bf16x8*)(&buf[0][(ja * 64 + g4 * 8) ^ ((ja & 7) << 3)]);
    bf16x8 qb1 = *(const bf16x8*)(&buf[0][(ja * 64 + 32 + g4 * 8) ^ ((ja & 7) << 3)]);
    sacc[jt] = __builtin_amdgcn_mfma_f32_16x16x32_bf16(ka0, qb0, sacc[jt], 0, 0, 0);
    sacc[jt] = __builtin_amdgcn_mfma_f32_16x16x32_bf16(ka1, qb1, sacc[jt], 0, 0, 0);
  }

  // ---- softmax over j ----
  float pr[4][4];
#pragma unroll
  for (int rr = 0; rr < 4; ++rr) {
    float m = fmaxf(fmaxf(sacc[0][rr], sacc[1][rr]), fmaxf(sacc[2][rr], sacc[3][rr]));
#pragma unroll
    for (int dd = 1; dd < 16; dd <<= 1) m = fmaxf(m, __shfl_xor(m, dd));
    float s = 0.f;
#pragma unroll
    for (int jt = 0; jt < 4; ++jt) {
      pr[jt][rr] = __expf(sacc[jt][rr] - m);
      s += pr[jt][rr];
    }
#pragma unroll
    for (int dd = 1; dd < 16; dd <<= 1) s += __shfl_xor(s, dd);
    float inv = 1.0f / s;
#pragma unroll
    for (int jt = 0; jt < 4; ++jt) pr[jt][rr] *= inv;
  }
  __syncthreads();                   // Q,K reads done

  // ---- write P into dead K slot ----
#pragma unroll
  for (int jt = 0; jt < 4; ++jt)
#pragma unroll
    for (int rr = 0; rr < 4; ++rr) {
      int i = i0 + 4 * g4 + rr;
      int j = jt * 16 + lr;
      buf[1][(i * 64 + j) ^ ((i & 7) << 3)] = (__bf16)pr[jt][rr];
    }
  __syncthreads();                   // P visible

  // ---- PV: pv[i][w] = sum_j P[i][j] V[j][w] ----
  f32x4 pacc[4];
#pragma unroll
  for (int wt = 0; wt < 4; ++wt) pacc[wt] = zero4;
  bf16x8 aa0, aa1;
  {
    int ia = i0 + lr;
    aa0 = *(const bf16x8*)(&buf[1][(ia * 64 + g4 * 8) ^ ((ia & 7) << 3)]);
    aa1 = *(const bf16x8*)(&buf[1][(ia * 64 + 32 + g4 * 8) ^ ((ia & 7) << 3)]);
  }
#pragma unroll
  for (int wt = 0; wt < 4; ++wt) {
    int wrow = wt * 16 + lr;
    bf16x8 vb0 = *(const bf16x8*)(&buf[2][(wrow * 64 + g4 * 8) ^ ((wrow & 7) << 3)]);
    bf16x8 vb1 = *(const bf16x8*)(&buf[2][(wrow * 64 + 32 + g4 * 8) ^ ((wrow & 7) << 3)]);
    pacc[wt] = __builtin_amdgcn_mfma_f32_16x16x32_bf16(aa0, vb0, pacc[wt], 0, 0, 0);
    pacc[wt] = __builtin_amdgcn_mfma_f32_16x16x32_bf16(aa1, vb1, pacc[wt], 0, 0, 0);
  }
  __syncthreads();                   // P,Vt reads done

  // ---- bounce PV fp32 through dead Q+K slots ----
  float* fb = (float*)&buf[0][0];    // 8192 bf16 = 4096 floats
#pragma unroll
  for (int wt = 0; wt < 4; ++wt)
#pragma unroll
    for (int rr = 0; rr < 4; ++rr) {
      int i = i0 + 4 * g4 + rr;
      int w = wt * 16 + lr;
      fb[(i * 64 + w) ^ ((i & 7) << 2)] = pacc[wt][rr];
    }
  __syncthreads();                   // bounce visible

  // ---- vectorized epilogue: out = gamma*pv + x ----
  {
    int oc = fp * NHEAD + np;
    float gm = gamma[np];
    int ib = t >> 2;                 // row index of this thread's 16 floats
    int xs_ = ((ib & 7) << 2);
    f32x4 p0 = *(const f32x4*)(fb + ((t * 16 + 0) ^ xs_));
    f32x4 p1 = *(const f32x4*)(fb + ((t * 16 + 4) ^ xs_));
    f32x4 p2 = *(const f32x4*)(fb + ((t * 16 + 8) ^ xs_));
    f32x4 p3 = *(const f32x4*)(fb + ((t * 16 + 12) ^ xs_));
    f32x4 o0, o1, o2v, o3;
#pragma unroll
    for (int j = 0; j < 4; ++j) {
      o0[j]  = gm * p0[j] + xpre[0][j];
      o1[j]  = gm * p1[j] + xpre[1][j];
      o2v[j] = gm * p2[j] + xpre[2][j];
      o3[j]  = gm * p3[j] + xpre[3][j];
    }
    float* op = out + (((size_t)b * 320 + oc) * 8 + d) * 4096 + t * 16;
    *(f32x4*)(op + 0)  = o0;
    *(f32x4*)(op + 4)  = o1;
    *(f32x4*)(op + 8)  = o2v;
    *(f32x4*)(op + 12) = o3;
  }
}

extern "C" void kernel_launch(void* const* d_in, const int* in_sizes, int n_in,
                              void* d_out, int out_size, void* d_ws, size_t ws_size,
                              hipStream_t stream) {
  const float* x     = (const float*)d_in[0];
  const float* W     = (const float*)d_in[1];
  const float* bias  = (const float*)d_in[2];
  const float* gamma = (const float*)d_in[3];
  float* out = (float*)d_out;

  // per (b,d) slice: xbf = 524288 B ; qkv = 7864320 B
  const size_t per_slice = 524288 + 7864320;   // 8 MB
  int S = (int)(ws_size / per_slice);
  if (S > 32) S = 32;
  if (S < 1)  S = 1;
  __bf16* xbf = (__bf16*)d_ws;
  __bf16* qkv = (__bf16*)((char*)d_ws + (size_t)S * 524288);

  for (int sb = 0; sb < 32; sb += S) {
    int sc = 32 - sb; if (sc > S) sc = S;
    k0_xpose<<<16  * sc, 256, 0, stream>>>(x, xbf, sb);
    k1_qkv  <<<240 * sc, 256, 0, stream>>>(xbf, W, bias, qkv, sb);
    k2_attn <<<320 * sc, 256, 0, stream>>>(qkv, x, gamma, out, sb);
  }
}